// Round 1
// baseline (77.071 us; speedup 1.0000x reference)
//
#include <hip/hip_runtime.h>

// QuantumFeatureMap, N_QUBITS=4, ALPHA=1.57 — closed form.
// After the RY layer the state is a product state; the CNOT ring only permutes
// basis states (GF(2)-linear), so every diagonal Z/ZZ observable pulls back to
// a product of per-qubit z's whose expectation is t_q = cos(ALPHA*x_q):
//   <Z0>=t1t2t3  <Z1>=t0t1  <Z2>=t0t1t2  <Z3>=t0t1t2t3
//   <Z0Z1>=t0t2t3 <Z0Z2>=t0t3 <Z0Z3>=t0 <Z1Z2>=t2 <Z1Z3>=t2t3 <Z2Z3>=t3
//
// Memory-bound: 16 B in + 40 B out per row. Wave-local LDS staging (no block
// barrier) re-packs the stride-10 row outputs into coalesced 16B stores.
//
// v2 vs v1: 2 rows/thread (128 rows/wave). Readback is now EXACTLY 5 v4f per
// lane — all stores full-wave, no divergent lane<32 tail, no per-store guards
// in the (always-taken for B%512==0) fast path. LDS writes are 5x ds_write_b64
// per row instead of 10x b32. LDS = 20 KB/block -> exactly 8 blocks/CU
// (160 KB) = 32 waves/CU. Grid halves to 2048 blocks.

#define QFM_ALPHA 1.57f

typedef float v4f __attribute__((ext_vector_type(4)));
typedef float v2f __attribute__((ext_vector_type(2)));

__device__ __forceinline__ void qfm_row(float* __restrict__ r, v4f v) {
    float t0 = __cosf(QFM_ALPHA * v.x);
    float t1 = __cosf(QFM_ALPHA * v.y);
    float t2 = __cosf(QFM_ALPHA * v.z);
    float t3 = __cosf(QFM_ALPHA * v.w);
    float t01 = t0 * t1, t23 = t2 * t3;
    // r is 8B-aligned (lane*10 floats = 40 B multiples): 5x ds_write_b64.
    v2f* w = (v2f*)r;
    w[0] = (v2f){t1 * t23, t01};        // <Z0>,   <Z1>
    w[1] = (v2f){t01 * t2, t01 * t23};  // <Z2>,   <Z3>
    w[2] = (v2f){t0 * t23, t0 * t3};    // <Z0Z1>, <Z0Z2>
    w[3] = (v2f){t0, t2};               // <Z0Z3>, <Z1Z2>
    w[4] = (v2f){t23, t3};              // <Z1Z3>, <Z2Z3>
}

__global__ __launch_bounds__(256) void qfm_kernel(const v4f* __restrict__ x,
                                                  v4f* __restrict__ out4,
                                                  int B) {
    __shared__ v4f lds4[1280];          // 4 waves * 320 v4f (128 rows * 10 floats)
    float* lds = (float*)lds4;

    int tid  = threadIdx.x;
    int wave = tid >> 6;
    int lane = tid & 63;
    int rowBase = blockIdx.x * 512 + wave * 128;   // wave's first row

    // Lane l owns rows (rowBase+l) and (rowBase+64+l):
    // LDS floats [l*10, l*10+10) and [640+l*10, 640+l*10+10) of the wave slab.
    float* r0 = &lds[wave * 1280 + lane * 10];
    float* r1 = r0 + 640;

    const v4f* slab = &lds4[wave * 320];
    int base = blockIdx.x * 1280 + wave * 320;     // v4f units in out

    if (blockIdx.x * 512 + 512 <= B) {
        // Fast path: whole block in range (always, when B % 512 == 0).
        v4f va = __builtin_nontemporal_load(&x[rowBase + lane]);       // coalesced 16B/lane
        v4f vb = __builtin_nontemporal_load(&x[rowBase + 64 + lane]);
        qfm_row(r0, va);
        qfm_row(r1, vb);
        // No __syncthreads: readback touches only this wave's own slab;
        // within-wave LDS RAW ordering is enforced by lgkmcnt waits.
        #pragma unroll
        for (int j = 0; j < 5; ++j) {
            v4f v = slab[lane + 64 * j];                               // conflict-free b128
            __builtin_nontemporal_store(v, &out4[base + lane + 64 * j]); // coalesced 1KB/instr
        }
    } else {
        // Tail block (B % 512 != 0): guarded loads/stores.
        int b0 = rowBase + lane, b1 = rowBase + 64 + lane;
        v4f z = {0.f, 0.f, 0.f, 0.f};
        v4f va = (b0 < B) ? x[b0] : z;
        v4f vb = (b1 < B) ? x[b1] : z;
        qfm_row(r0, va);
        qfm_row(r1, vb);
        int limit = (B * 10 + 3) >> 2;
        #pragma unroll
        for (int j = 0; j < 5; ++j) {
            int o = base + lane + 64 * j;
            if (o < limit) __builtin_nontemporal_store(slab[lane + 64 * j], &out4[o]);
        }
    }
}

extern "C" void kernel_launch(void* const* d_in, const int* in_sizes, int n_in,
                              void* d_out, int out_size, void* d_ws, size_t ws_size,
                              hipStream_t stream) {
    const v4f* x = (const v4f*)d_in[0];
    v4f* out = (v4f*)d_out;
    int B = in_sizes[0] / 4;                      // rows of [B,4]
    int grid = (B + 511) / 512;                   // 512 rows per block
    qfm_kernel<<<grid, 256, 0, stream>>>(x, out, B);
}

// Round 2
// 75.490 us; speedup vs baseline: 1.0210x; 1.0210x over previous
//
#include <hip/hip_runtime.h>

// QuantumFeatureMap, N_QUBITS=4, ALPHA=1.57 — closed form.
// After the RY layer the state is a product state; the CNOT ring only permutes
// basis states (GF(2)-linear), so every diagonal Z/ZZ observable pulls back to
// a product of per-qubit z's whose expectation is t_q = cos(ALPHA*x_q):
//   <Z0>=t1t2t3  <Z1>=t0t1  <Z2>=t0t1t2  <Z3>=t0t1t2t3
//   <Z0Z1>=t0t2t3 <Z0Z2>=t0t3 <Z0Z3>=t0 <Z1Z2>=t2 <Z1Z3>=t2t3 <Z2Z3>=t3
// Memory-bound: 16 B in + 40 B out per row. Wave-local LDS staging (no block
// barrier) re-packs the stride-10 row outputs into coalesced 16B stores.
//
// NOTE (session journal): this exact kernel measured 74.70 µs; a 2-rows/thread
// variant with full-wave stores and half the LDS instructions measured 77.07 µs.
// Delta is inside the ±3% harness noise band — the timed region is dominated by
// a fixed ~45 µs 268 MB poison-fill (75% HBM peak) plus reset memsets; the
// kernel's own ~59 MB of traffic is ~10 µs at achieved HBM BW. Keeping the
// measured-best version.

#define QFM_ALPHA 1.57f

typedef float v4f __attribute__((ext_vector_type(4)));   // native vector: ok for nontemporal builtins

__global__ __launch_bounds__(256) void qfm_kernel(const v4f* __restrict__ x,
                                                  v4f* __restrict__ out4,
                                                  int B) {
    __shared__ v4f lds4[640];               // 4 waves * 160 v4f (64 rows * 10 floats each)
    float* lds = (float*)lds4;

    int tid  = threadIdx.x;
    int wave = tid >> 6;
    int lane = tid & 63;
    int b = blockIdx.x * 256 + tid;

    float t0 = 1.f, t1 = 1.f, t2 = 1.f, t3 = 1.f;
    if (b < B) {
        v4f v = x[b];                       // coalesced 16B/lane load
        t0 = __cosf(QFM_ALPHA * v.x);
        t1 = __cosf(QFM_ALPHA * v.y);
        t2 = __cosf(QFM_ALPHA * v.z);
        t3 = __cosf(QFM_ALPHA * v.w);
    }

    float t01 = t0 * t1;
    float t23 = t2 * t3;

    // Wave-local slab: lane l owns floats [l*10, l*10+10) of its wave's 640-float slab.
    float* r = &lds[wave * 640 + lane * 10];
    r[0] = t1 * t23;        // <Z0>
    r[1] = t01;             // <Z1>
    r[2] = t01 * t2;        // <Z2>
    r[3] = t01 * t23;       // <Z3>
    r[4] = t0 * t23;        // <Z0Z1>
    r[5] = t0 * t3;         // <Z0Z2>
    r[6] = t0;              // <Z0Z3>
    r[7] = t2;              // <Z1Z2>
    r[8] = t23;             // <Z1Z3>
    r[9] = t3;              // <Z2Z3>
    // No __syncthreads: the readback below only touches this wave's own slab,
    // and within-wave LDS ordering is enforced by lgkmcnt waits.

    const v4f* slab = &lds4[wave * 160];
    int base  = blockIdx.x * 640 + wave * 160;          // v4f units
    int limit = (B * 10 + 3) >> 2;                      // tail guard (exact fit when B%256==0)

    v4f v0 = slab[lane];
    v4f v1 = slab[lane + 64];
    if (base + lane      < limit) __builtin_nontemporal_store(v0, &out4[base + lane]);
    if (base + lane + 64 < limit) __builtin_nontemporal_store(v1, &out4[base + lane + 64]);
    if (lane < 32) {
        v4f v2 = slab[lane + 128];
        if (base + lane + 128 < limit) __builtin_nontemporal_store(v2, &out4[base + lane + 128]);
    }
}

extern "C" void kernel_launch(void* const* d_in, const int* in_sizes, int n_in,
                              void* d_out, int out_size, void* d_ws, size_t ws_size,
                              hipStream_t stream) {
    const v4f* x = (const v4f*)d_in[0];
    v4f* out = (v4f*)d_out;
    int B = in_sizes[0] / 4;                      // rows of [B,4]
    int grid = (B + 255) / 256;
    qfm_kernel<<<grid, 256, 0, stream>>>(x, out, B);
}